// Round 3
// baseline (603.893 us; speedup 1.0000x reference)
//
#include <hip/hip_runtime.h>

typedef unsigned short u16;
typedef unsigned int u32;
typedef __attribute__((ext_vector_type(8))) __bf16 bf16x8;
typedef __attribute__((ext_vector_type(4))) float f32x4;
typedef __attribute__((ext_vector_type(4))) u32 u32x4;
typedef __attribute__((ext_vector_type(2))) u32 u32x2;

#define HW 16384
#define C 128
#define NB 16
#define LSTR 136   // u16 elems per LDS row (staging / bf16 epilogue)
#define FSTR 132   // f32 elems per LDS row (fp32 epilogue)

__device__ __forceinline__ u16 f2bf(float f) {
    __bf16 h = (__bf16)f;
    union { __bf16 h; u16 u; } c; c.h = h; return c.u;
}
__device__ __forceinline__ float bf2f(u16 u) {
    union { u32 i; float f; } c; c.i = ((u32)u) << 16; return c.f;
}

__device__ __forceinline__ bf16x8 load_wrow(const float* p) {
    f32x4 a = *(const f32x4*)p, b = *(const f32x4*)(p + 4);
    bf16x8 r;
    #pragma unroll
    for (int i = 0; i < 4; ++i) { r[i] = (__bf16)a[i]; r[i + 4] = (__bf16)b[i]; }
    return r;
}
__device__ __forceinline__ bf16x8 load_wrow(const u16* p) {
    return *(const bf16x8*)p;
}

// Y[:, n0:n0+128] = W(128x128, k-contig rows) @ X(fp32 128xHW) + bias.
// WT in {float,u16(bf16)}; YT in {u16(bf16), float}. In-place safe (Y==X).
template <typename WT, typename YT>
__device__ __forceinline__ void gemm128(
    const WT* __restrict__ W, const float* __restrict__ X,
    const float* __restrict__ bias, YT* __restrict__ Y,
    int n0, u16* lds)
{
    const int tid  = threadIdx.x;
    const int lane = tid & 63;
    const int wave = tid >> 6;
    const int m_lo = lane & 15;
    const int quad = lane >> 4;

    // ---- stage X^T tile (fp32 -> bf16), lds[n][k], XOR-swizzled 8-elem chunks ----
    #pragma unroll
    for (int r = 0; r < 2; ++r) {
        int idx = tid + 256 * r;        // 0..511
        int n4  = idx & 31;             // group of 4 columns
        int kc  = idx >> 5;             // chunk of 8 k-rows
        const float* src = X + (size_t)(kc * 8) * HW + n0 + n4 * 4;
        f32x4 v[8];
        #pragma unroll
        for (int j = 0; j < 8; ++j) v[j] = *(const f32x4*)(src + (size_t)j * HW);
        #pragma unroll
        for (int t = 0; t < 4; ++t) {
            union { u16 u[8]; u32x4 q; } e;
            #pragma unroll
            for (int j = 0; j < 8; ++j) e.u[j] = f2bf(v[j][t]);
            int row = n4 * 4 + t;
            int cs  = kc ^ (n4 & 7);
            *(u32x4*)(lds + row * LSTR + cs * 8) = e.q;
        }
    }
    __syncthreads();

    f32x4 acc[2][8];
    #pragma unroll
    for (int mt = 0; mt < 2; ++mt)
        #pragma unroll
        for (int nt = 0; nt < 8; ++nt) {
            f32x4 z = {0.f, 0.f, 0.f, 0.f};
            acc[mt][nt] = z;
        }

    #pragma unroll
    for (int ks = 0; ks < 4; ++ks) {
        const int k0 = ks * 32 + quad * 8;
        bf16x8 af[2];
        #pragma unroll
        for (int mt = 0; mt < 2; ++mt) {
            int m = wave * 32 + mt * 16 + m_lo;
            af[mt] = load_wrow(W + (size_t)m * 128 + k0);
        }
        #pragma unroll
        for (int nt = 0; nt < 8; ++nt) {
            int n  = nt * 16 + m_lo;
            int cs = (ks * 4 + quad) ^ ((n >> 2) & 7);
            bf16x8 bfrag = *(const bf16x8*)(lds + n * LSTR + cs * 8);
            #pragma unroll
            for (int mt = 0; mt < 2; ++mt)
                acc[mt][nt] = __builtin_amdgcn_mfma_f32_16x16x32_bf16(
                    af[mt], bfrag, acc[mt][nt], 0, 0, 0);
        }
    }
    __syncthreads();   // staging data dead; reuse LDS for epilogue

    if constexpr (sizeof(YT) == 2) {
        // bf16 output: single-phase reorder
        #pragma unroll
        for (int mt = 0; mt < 2; ++mt)
            #pragma unroll
            for (int nt = 0; nt < 8; ++nt)
                #pragma unroll
                for (int r = 0; r < 4; ++r) {
                    int m = wave * 32 + mt * 16 + quad * 4 + r;
                    int n = nt * 16 + m_lo;
                    lds[m * LSTR + n] = f2bf(acc[mt][nt][r] + bias[m]);
                }
        __syncthreads();
        #pragma unroll
        for (int i = 0; i < 8; ++i) {
            int idx = tid + 256 * i;    // 0..2047
            int row = idx >> 4;
            int ch  = idx & 15;
            u32x4 v = *(u32x4*)(lds + row * LSTR + ch * 8);
            *(u32x4*)(Y + (size_t)row * HW + n0 + ch * 8) = v;
        }
    } else {
        // fp32 output: two-phase (64 rows per phase fits LDS)
        float* ldsf = (float*)lds;
        #pragma unroll
        for (int ph = 0; ph < 2; ++ph) {
            if ((wave >> 1) == ph) {
                #pragma unroll
                for (int mt = 0; mt < 2; ++mt)
                    #pragma unroll
                    for (int nt = 0; nt < 8; ++nt)
                        #pragma unroll
                        for (int r = 0; r < 4; ++r) {
                            int m = wave * 32 + mt * 16 + quad * 4 + r;
                            int n = nt * 16 + m_lo;
                            ldsf[(m & 63) * FSTR + n] = acc[mt][nt][r] + bias[m];
                        }
            }
            __syncthreads();
            #pragma unroll
            for (int i = 0; i < 8; ++i) {
                int idx = tid + 256 * i;   // 0..2047
                int row = idx >> 5;        // 0..63
                int c4  = idx & 31;
                f32x4 vv = *(const f32x4*)(ldsf + row * FSTR + c4 * 4);
                *(f32x4*)(Y + (size_t)(ph * 64 + row) * HW + n0 + c4 * 4) = vv;
            }
            __syncthreads();
        }
    }
}

// ---- K1a: q,k conv1x1 (fp32 x -> bf16 planes in d_out) ----
__global__ __launch_bounds__(256) void k_conv_qk(
    const float* __restrict__ x,
    const float* __restrict__ qw, const float* __restrict__ qbias,
    const float* __restrict__ kw, const float* __restrict__ kbias,
    u16* __restrict__ qpl, u16* __restrict__ kpl)
{
    __shared__ __align__(16) u16 lds[128 * LSTR];
    int b = blockIdx.z, s = blockIdx.y;
    const float* W    = s ? kw : qw;
    const float* bias = s ? kbias : qbias;
    u16* Y = (s ? kpl : qpl) + (size_t)b * C * HW;
    gemm128(W, x + (size_t)b * C * HW, bias, Y, blockIdx.x * 128, lds);
}

// ---- K1b: v conv1x1, fp32 in-place into x ----
__global__ __launch_bounds__(256) void k_conv_v(
    float* __restrict__ x, const float* __restrict__ vw, const float* __restrict__ vbias)
{
    __shared__ __align__(16) u16 lds[128 * LSTR];
    int b = blockIdx.z;
    float* Xb = x + (size_t)b * C * HW;
    gemm128(vw, Xb, vbias, Xb, blockIdx.x * 128, lds);
}

// ---- K2a: depthwise 3x3 on q,k bf16 planes (in-place) + sum-of-squares ----
__global__ __launch_bounds__(256) void k_dw_qk(
    u16* __restrict__ qpl, u16* __restrict__ kpl,
    const float* __restrict__ qdw, const float* __restrict__ qdb,
    const float* __restrict__ kdw, const float* __restrict__ kdb,
    float* __restrict__ norm2)
{
    __shared__ __align__(16) u16 pl[HW];
    __shared__ float red[256];
    int pid = blockIdx.x;           // s*2048 + b*128 + c
    int s = pid >> 11, bc = pid & 2047, c = bc & 127;
    u16* plane = (s ? kpl : qpl) + (size_t)bc * HW;
    const float* dw = (s ? kdw : qdw) + c * 9;
    float bias = (s ? kdb : qdb)[c];
    int tid = threadIdx.x;

    #pragma unroll
    for (int i = 0; i < 8; ++i) {
        int idx = tid + 256 * i;
        *(u32x4*)(pl + idx * 8) = *(const u32x4*)(plane + idx * 8);
    }
    float w[9];
    #pragma unroll
    for (int j = 0; j < 9; ++j) w[j] = dw[j];
    __syncthreads();

    float ssq = 0.f;
    for (int i = 0; i < 16; ++i) {
        int p0 = (tid + 256 * i) * 4;
        int py = p0 >> 7, px0 = p0 & 127;
        float nb[3][6];
        #pragma unroll
        for (int dy = 0; dy < 3; ++dy) {
            int yy = py + dy - 1;
            bool yok = (yy >= 0) && (yy < 128);
            int ya = yok ? yy : 0;
            #pragma unroll
            for (int j = 0; j < 6; ++j) {
                int xx = px0 + j - 1;
                bool ok = yok && (xx >= 0) && (xx < 128);
                int xa = (xx >= 0 && xx < 128) ? xx : 0;
                float vv = bf2f(pl[ya * 128 + xa]);
                nb[dy][j] = ok ? vv : 0.f;
            }
        }
        u16 o[4];
        #pragma unroll
        for (int t = 0; t < 4; ++t) {
            float acc = bias;
            #pragma unroll
            for (int dy = 0; dy < 3; ++dy)
                #pragma unroll
                for (int dx = 0; dx < 3; ++dx)
                    acc += w[dy * 3 + dx] * nb[dy][t + dx];
            ssq += acc * acc;
            o[t] = f2bf(acc);
        }
        u32x2 pr;
        pr.x = (u32)o[0] | ((u32)o[1] << 16);
        pr.y = (u32)o[2] | ((u32)o[3] << 16);
        *(u32x2*)(plane + p0) = pr;
    }
    red[tid] = ssq;
    __syncthreads();
    for (int off = 128; off > 0; off >>= 1) {
        if (tid < off) red[tid] += red[tid + off];
        __syncthreads();
    }
    if (tid == 0) norm2[s * (NB * C) + bc] = red[0];
}

// ---- K2b: depthwise 3x3 on v fp32 planes (in-place in x) ----
__global__ __launch_bounds__(256) void k_dw_v(
    float* __restrict__ x, const float* __restrict__ vdw, const float* __restrict__ vdb)
{
    __shared__ __align__(16) float pl[HW];   // 64 KiB
    int bc = blockIdx.x;                     // b*128 + c
    int c = bc & 127;
    float* plane = x + (size_t)bc * HW;
    const float* dw = vdw + c * 9;
    float bias = vdb[c];
    int tid = threadIdx.x;

    #pragma unroll
    for (int i = 0; i < 16; ++i) {
        int idx = tid + 256 * i;
        *(f32x4*)(pl + idx * 4) = *(const f32x4*)(plane + idx * 4);
    }
    float w[9];
    #pragma unroll
    for (int j = 0; j < 9; ++j) w[j] = dw[j];
    __syncthreads();

    for (int i = 0; i < 16; ++i) {
        int p0 = (tid + 256 * i) * 4;
        int py = p0 >> 7, px0 = p0 & 127;
        float nb[3][6];
        #pragma unroll
        for (int dy = 0; dy < 3; ++dy) {
            int yy = py + dy - 1;
            bool yok = (yy >= 0) && (yy < 128);
            int ya = yok ? yy : 0;
            #pragma unroll
            for (int j = 0; j < 6; ++j) {
                int xx = px0 + j - 1;
                bool ok = yok && (xx >= 0) && (xx < 128);
                int xa = (xx >= 0 && xx < 128) ? xx : 0;
                float vv = pl[ya * 128 + xa];
                nb[dy][j] = ok ? vv : 0.f;
            }
        }
        f32x4 o;
        #pragma unroll
        for (int t = 0; t < 4; ++t) {
            float acc = bias;
            #pragma unroll
            for (int dy = 0; dy < 3; ++dy)
                #pragma unroll
                for (int dx = 0; dx < 3; ++dx)
                    acc += w[dy * 3 + dx] * nb[dy][t + dx];
            o[t] = acc;
        }
        *(f32x4*)(plane + p0) = o;
    }
}

// ---- K3: Gram G[b] += q_b @ k_b^T  (split-K=16, bf16 MFMA, fp32 atomics) ----
__global__ __launch_bounds__(256) void k_gram(
    const u16* __restrict__ q, const u16* __restrict__ k, float* __restrict__ G)
{
    int kz = blockIdx.x, b = blockIdx.y;
    const u16* qb = q + (size_t)b * C * HW;
    const u16* kb = k + (size_t)b * C * HW;
    int lane = threadIdx.x & 63, wave = threadIdx.x >> 6;
    int m_lo = lane & 15, quad = lane >> 4;
    f32x4 acc[2][8];
    #pragma unroll
    for (int mt = 0; mt < 2; ++mt)
        #pragma unroll
        for (int nt = 0; nt < 8; ++nt) {
            f32x4 z = {0.f, 0.f, 0.f, 0.f};
            acc[mt][nt] = z;
        }
    for (int step = 0; step < 32; ++step) {
        int kk = kz * 1024 + step * 32 + quad * 8;
        bf16x8 a0 = *(const bf16x8*)(qb + (size_t)(wave * 32 + m_lo) * HW + kk);
        bf16x8 a1 = *(const bf16x8*)(qb + (size_t)(wave * 32 + 16 + m_lo) * HW + kk);
        #pragma unroll
        for (int nt = 0; nt < 8; ++nt) {
            bf16x8 bf = *(const bf16x8*)(kb + (size_t)(nt * 16 + m_lo) * HW + kk);
            acc[0][nt] = __builtin_amdgcn_mfma_f32_16x16x32_bf16(a0, bf, acc[0][nt], 0, 0, 0);
            acc[1][nt] = __builtin_amdgcn_mfma_f32_16x16x32_bf16(a1, bf, acc[1][nt], 0, 0, 0);
        }
    }
    float* Gb = G + (size_t)b * C * C;
    #pragma unroll
    for (int mt = 0; mt < 2; ++mt)
        #pragma unroll
        for (int nt = 0; nt < 8; ++nt)
            #pragma unroll
            for (int r = 0; r < 4; ++r) {
                int m = wave * 32 + mt * 16 + quad * 4 + r;
                int n = nt * 16 + m_lo;
                atomicAdd(&Gb[m * C + n], acc[mt][nt][r]);
            }
}

// ---- K4a: normalize + row softmax in-place on G ----
__global__ __launch_bounds__(128) void k_softmax(float* __restrict__ G, const float* __restrict__ norm2)
{
    __shared__ float red[128];
    int c = blockIdx.x, b = blockIdx.y, d = threadIdx.x;
    float* row = G + ((size_t)b * C + c) * C;
    float nq = fmaxf(sqrtf(norm2[b * C + c]), 1e-12f);
    float nk = fmaxf(sqrtf(norm2[NB * C + b * C + d]), 1e-12f);
    float sv = row[d] / (nq * nk);
    red[d] = sv; __syncthreads();
    for (int off = 64; off > 0; off >>= 1) {
        if (d < off) red[d] = fmaxf(red[d], red[d + off]);
        __syncthreads();
    }
    float mx = red[0]; __syncthreads();
    float e = __expf(sv - mx);
    red[d] = e; __syncthreads();
    for (int off = 64; off > 0; off >>= 1) {
        if (d < off) red[d] += red[d + off];
        __syncthreads();
    }
    row[d] = e / red[0];
}

// ---- K4b: M_b = aw @ A_b (bf16 out) ----
__global__ __launch_bounds__(256) void k_mproj(
    const float* __restrict__ G, const float* __restrict__ aw, u16* __restrict__ M)
{
    __shared__ float As[128 * 16];
    int b = blockIdx.y, d0 = blockIdx.x * 16, tid = threadIdx.x;
    const float* A = G + (size_t)b * C * C;
    #pragma unroll
    for (int i = 0; i < 8; ++i) {
        int idx = tid + 256 * i;
        int cc = idx >> 4, dd = idx & 15;
        As[idx] = A[cc * C + d0 + dd];
    }
    __syncthreads();
    #pragma unroll
    for (int i = 0; i < 8; ++i) {
        int idx = tid + 256 * i;
        int oo = idx >> 4, dd = idx & 15;
        float s = 0.f;
        for (int cc = 0; cc < 128; ++cc)
            s += aw[oo * C + cc] * As[cc * 16 + dd];
        M[((size_t)b * C + oo) * C + d0 + dd] = f2bf(s);
    }
}

// ---- K5: out = M_b @ v + ab (fp32 out; folds final conv1x1) ----
__global__ __launch_bounds__(256) void k_out(
    const u16* __restrict__ M, const float* __restrict__ xv,
    const float* __restrict__ ab, float* __restrict__ out)
{
    __shared__ __align__(16) u16 lds[128 * LSTR];
    int b = blockIdx.z;
    gemm128(M + (size_t)b * C * C, xv + (size_t)b * C * HW, ab,
            out + (size_t)b * C * HW, blockIdx.x * 128, lds);
}

extern "C" void kernel_launch(void* const* d_in, const int* in_sizes, int n_in,
                              void* d_out, int out_size, void* d_ws, size_t ws_size,
                              hipStream_t stream)
{
    float* x         = (float*)d_in[0];   // scribbled: becomes v (harness restores)
    const float* qw  = (const float*)d_in[1];
    const float* qbi = (const float*)d_in[2];
    const float* qdw = (const float*)d_in[3];
    const float* qdb = (const float*)d_in[4];
    const float* kw  = (const float*)d_in[5];
    const float* kbi = (const float*)d_in[6];
    const float* kdw = (const float*)d_in[7];
    const float* kdb = (const float*)d_in[8];
    const float* vw  = (const float*)d_in[9];
    const float* vbi = (const float*)d_in[10];
    const float* vdw = (const float*)d_in[11];
    const float* vdb = (const float*)d_in[12];
    const float* aw  = (const float*)d_in[13];
    const float* ab  = (const float*)d_in[14];

    // q,k bf16 planes live in d_out (dead after Gram; overwritten by K5)
    u16* qpl = (u16*)d_out;
    u16* kpl = qpl + (size_t)NB * C * HW;

    // ws: < 2 MiB
    float* G     = (float*)d_ws;              // 16*128*128 fp32 = 1 MiB
    float* norm2 = G + (size_t)NB * C * C;    // 2*16*128 fp32
    u16*   M     = (u16*)(norm2 + 2 * NB * C);// 16*128*128 bf16 = 0.5 MiB

    hipMemsetAsync(G, 0, (size_t)NB * C * C * sizeof(float), stream);

    k_conv_qk<<<dim3(HW / 128, 2, NB), 256, 0, stream>>>(x, qw, qbi, kw, kbi, qpl, kpl);
    k_conv_v<<<dim3(HW / 128, 1, NB), 256, 0, stream>>>(x, vw, vbi);
    k_dw_qk<<<dim3(2 * NB * C), 256, 0, stream>>>(qpl, kpl, qdw, qdb, kdw, kdb, norm2);
    k_dw_v<<<dim3(NB * C), 256, 0, stream>>>(x, vdw, vdb);
    k_gram<<<dim3(16, NB), 256, 0, stream>>>(qpl, kpl, G);
    k_softmax<<<dim3(C, NB), 128, 0, stream>>>(G, norm2);
    k_mproj<<<dim3(8, NB), 256, 0, stream>>>(G, aw, M);
    k_out<<<dim3(HW / 128, 1, NB), 256, 0, stream>>>(M, x, ab, (float*)d_out);
}

// Round 4
// 551.429 us; speedup vs baseline: 1.0951x; 1.0951x over previous
//
#include <hip/hip_runtime.h>

typedef unsigned short u16;
typedef unsigned int u32;
typedef __attribute__((ext_vector_type(8))) __bf16 bf16x8;
typedef __attribute__((ext_vector_type(4))) float f32x4;
typedef __attribute__((ext_vector_type(4))) u32 u32x4;
typedef __attribute__((ext_vector_type(2))) u32 u32x2;

#define HW 16384
#define C 128
#define NB 16
#define LSTR 136   // u16 elems per LDS staging row
#define FSTR 132   // f32 elems per LDS row (fp32 epilogue)

__device__ __forceinline__ u16 f2bf(float f) {
    __bf16 h = (__bf16)f;
    union { __bf16 h; u16 u; } c; c.h = h; return c.u;
}
__device__ __forceinline__ float bf2f(u16 u) {
    union { u32 i; float f; } c; c.i = ((u32)u) << 16; return c.f;
}

__device__ __forceinline__ bf16x8 load_wrow(const float* p) {
    f32x4 a = *(const f32x4*)p, b = *(const f32x4*)(p + 4);
    bf16x8 r;
    #pragma unroll
    for (int i = 0; i < 4; ++i) { r[i] = (__bf16)a[i]; r[i + 4] = (__bf16)b[i]; }
    return r;
}
__device__ __forceinline__ bf16x8 load_wrow(const u16* p) {
    return *(const bf16x8*)p;
}

// 64 MFMA over the staged 128x128 LDS tile (XOR-swizzled), W k-contig 128x128
template <typename WT>
__device__ __forceinline__ void mfma_tile(
    const WT* __restrict__ W, const u16* lds,
    f32x4 (&acc)[2][8], int wave, int m_lo, int quad)
{
    #pragma unroll
    for (int mt = 0; mt < 2; ++mt)
        #pragma unroll
        for (int nt = 0; nt < 8; ++nt) {
            f32x4 z = {0.f, 0.f, 0.f, 0.f};
            acc[mt][nt] = z;
        }
    #pragma unroll
    for (int ks = 0; ks < 4; ++ks) {
        const int k0 = ks * 32 + quad * 8;
        bf16x8 af[2];
        #pragma unroll
        for (int mt = 0; mt < 2; ++mt) {
            int m = wave * 32 + mt * 16 + m_lo;
            af[mt] = load_wrow(W + (size_t)m * 128 + k0);
        }
        #pragma unroll
        for (int nt = 0; nt < 8; ++nt) {
            int n  = nt * 16 + m_lo;
            int cs = (ks * 4 + quad) ^ ((n >> 2) & 7);
            bf16x8 bfrag = *(const bf16x8*)(lds + n * LSTR + cs * 8);
            #pragma unroll
            for (int mt = 0; mt < 2; ++mt)
                acc[mt][nt] = __builtin_amdgcn_mfma_f32_16x16x32_bf16(
                    af[mt], bfrag, acc[mt][nt], 0, 0, 0);
        }
    }
}

// ---- K1: fused q,k,v conv1x1. Stage X once; 3 MFMA passes; direct stores.
// q,k -> bf16 planes (d_out); v -> fp32 in-place into x (column-disjoint safe).
__global__ __launch_bounds__(256) void k_conv_qkv(
    float* __restrict__ x,
    const float* __restrict__ qw, const float* __restrict__ qbi,
    const float* __restrict__ kw, const float* __restrict__ kbi,
    const float* __restrict__ vw, const float* __restrict__ vbi,
    u16* __restrict__ qpl, u16* __restrict__ kpl)
{
    __shared__ __align__(16) u16 lds[128 * LSTR];
    const int tid  = threadIdx.x;
    const int lane = tid & 63;
    const int wave = tid >> 6;
    const int m_lo = lane & 15;
    const int quad = lane >> 4;
    const int b  = blockIdx.z;
    const int n0 = blockIdx.x * 128;
    float* Xb = x + (size_t)b * C * HW;

    // stage X^T tile (fp32 -> bf16), lds[n][k], XOR-swizzled
    #pragma unroll
    for (int r = 0; r < 2; ++r) {
        int idx = tid + 256 * r;
        int n4  = idx & 31;
        int kc  = idx >> 5;
        const float* src = Xb + (size_t)(kc * 8) * HW + n0 + n4 * 4;
        f32x4 v[8];
        #pragma unroll
        for (int j = 0; j < 8; ++j) v[j] = *(const f32x4*)(src + (size_t)j * HW);
        #pragma unroll
        for (int t = 0; t < 4; ++t) {
            union { u16 u[8]; u32x4 q; } e;
            #pragma unroll
            for (int j = 0; j < 8; ++j) e.u[j] = f2bf(v[j][t]);
            int row = n4 * 4 + t;
            int cs  = kc ^ (n4 & 7);
            *(u32x4*)(lds + row * LSTR + cs * 8) = e.q;
        }
    }
    __syncthreads();

    f32x4 acc[2][8];

    // s = 0 (q) and s = 1 (k): bf16 direct stores
    #pragma unroll 1
    for (int s = 0; s < 2; ++s) {
        const float* W    = s ? kw : qw;
        const float* bias = s ? kbi : qbi;
        u16* Y = (s ? kpl : qpl) + (size_t)b * C * HW;
        mfma_tile(W, lds, acc, wave, m_lo, quad);
        #pragma unroll
        for (int mt = 0; mt < 2; ++mt)
            #pragma unroll
            for (int r = 0; r < 4; ++r) {
                int m = wave * 32 + mt * 16 + quad * 4 + r;
                float bm = bias[m];
                u16* rowp = Y + (size_t)m * HW + n0 + m_lo;
                #pragma unroll
                for (int nt = 0; nt < 8; ++nt)
                    rowp[nt * 16] = f2bf(acc[mt][nt][r] + bm);
            }
    }

    // s = 2 (v): fp32 in-place into x
    mfma_tile(vw, lds, acc, wave, m_lo, quad);
    #pragma unroll
    for (int mt = 0; mt < 2; ++mt)
        #pragma unroll
        for (int r = 0; r < 4; ++r) {
            int m = wave * 32 + mt * 16 + quad * 4 + r;
            float bm = vbi[m];
            float* rowp = Xb + (size_t)m * HW + n0 + m_lo;
            #pragma unroll
            for (int nt = 0; nt < 8; ++nt)
                rowp[nt * 16] = acc[mt][nt][r] + bm;
        }
}

// ---- K2: depthwise 3x3 on q,k bf16 planes (in-place) + sum-of-squares ----
__global__ __launch_bounds__(256) void k_dw_qk(
    u16* __restrict__ qpl, u16* __restrict__ kpl,
    const float* __restrict__ qdw, const float* __restrict__ qdb,
    const float* __restrict__ kdw, const float* __restrict__ kdb,
    float* __restrict__ norm2)
{
    __shared__ __align__(16) u16 pl[HW];
    __shared__ float red[256];
    int pid = blockIdx.x;
    int s = pid >> 11, bc = pid & 2047, c = bc & 127;
    u16* plane = (s ? kpl : qpl) + (size_t)bc * HW;
    const float* dw = (s ? kdw : qdw) + c * 9;
    float bias = (s ? kdb : qdb)[c];
    int tid = threadIdx.x;

    #pragma unroll
    for (int i = 0; i < 8; ++i) {
        int idx = tid + 256 * i;
        *(u32x4*)(pl + idx * 8) = *(const u32x4*)(plane + idx * 8);
    }
    float w[9];
    #pragma unroll
    for (int j = 0; j < 9; ++j) w[j] = dw[j];
    __syncthreads();

    float ssq = 0.f;
    for (int i = 0; i < 16; ++i) {
        int p0 = (tid + 256 * i) * 4;
        int py = p0 >> 7, px0 = p0 & 127;
        float nb[3][6];
        #pragma unroll
        for (int dy = 0; dy < 3; ++dy) {
            int yy = py + dy - 1;
            bool yok = (yy >= 0) && (yy < 128);
            int ya = yok ? yy : 0;
            #pragma unroll
            for (int j = 0; j < 6; ++j) {
                int xx = px0 + j - 1;
                bool ok = yok && (xx >= 0) && (xx < 128);
                int xa = (xx >= 0 && xx < 128) ? xx : 0;
                float vv = bf2f(pl[ya * 128 + xa]);
                nb[dy][j] = ok ? vv : 0.f;
            }
        }
        u16 o[4];
        #pragma unroll
        for (int t = 0; t < 4; ++t) {
            float acc = bias;
            #pragma unroll
            for (int dy = 0; dy < 3; ++dy)
                #pragma unroll
                for (int dx = 0; dx < 3; ++dx)
                    acc += w[dy * 3 + dx] * nb[dy][t + dx];
            ssq += acc * acc;
            o[t] = f2bf(acc);
        }
        u32x2 pr;
        pr.x = (u32)o[0] | ((u32)o[1] << 16);
        pr.y = (u32)o[2] | ((u32)o[3] << 16);
        *(u32x2*)(plane + p0) = pr;
    }
    red[tid] = ssq;
    __syncthreads();
    for (int off = 128; off > 0; off >>= 1) {
        if (tid < off) red[tid] += red[tid + off];
        __syncthreads();
    }
    if (tid == 0) norm2[s * (NB * C) + bc] = red[0];
}

// ---- K3: Gram, split-K=16 x split-N=2 (512 blocks), fp32 atomics into G ----
__global__ __launch_bounds__(256) void k_gram(
    const u16* __restrict__ q, const u16* __restrict__ k, float* __restrict__ G)
{
    int kz = blockIdx.x, nz = blockIdx.y, b = blockIdx.z;
    const u16* qb = q + (size_t)b * C * HW;
    const u16* kb = k + (size_t)b * C * HW;
    int lane = threadIdx.x & 63, wave = threadIdx.x >> 6;
    int m_lo = lane & 15, quad = lane >> 4;
    f32x4 acc[2][4];
    #pragma unroll
    for (int mt = 0; mt < 2; ++mt)
        #pragma unroll
        for (int nt = 0; nt < 4; ++nt) {
            f32x4 z = {0.f, 0.f, 0.f, 0.f};
            acc[mt][nt] = z;
        }
    for (int step = 0; step < 32; ++step) {
        int kk = kz * 1024 + step * 32 + quad * 8;
        bf16x8 a0 = *(const bf16x8*)(qb + (size_t)(wave * 32 + m_lo) * HW + kk);
        bf16x8 a1 = *(const bf16x8*)(qb + (size_t)(wave * 32 + 16 + m_lo) * HW + kk);
        #pragma unroll
        for (int nt = 0; nt < 4; ++nt) {
            bf16x8 bf = *(const bf16x8*)(kb + (size_t)(nz * 64 + nt * 16 + m_lo) * HW + kk);
            acc[0][nt] = __builtin_amdgcn_mfma_f32_16x16x32_bf16(a0, bf, acc[0][nt], 0, 0, 0);
            acc[1][nt] = __builtin_amdgcn_mfma_f32_16x16x32_bf16(a1, bf, acc[1][nt], 0, 0, 0);
        }
    }
    float* Gb = G + (size_t)b * C * C;
    #pragma unroll
    for (int mt = 0; mt < 2; ++mt)
        #pragma unroll
        for (int nt = 0; nt < 4; ++nt)
            #pragma unroll
            for (int r = 0; r < 4; ++r) {
                int m = wave * 32 + mt * 16 + quad * 4 + r;
                int n = nz * 64 + nt * 16 + m_lo;
                atomicAdd(&Gb[m * C + n], acc[mt][nt][r]);
            }
}

// ---- K4a: normalize + row softmax in-place on G ----
__global__ __launch_bounds__(128) void k_softmax(float* __restrict__ G, const float* __restrict__ norm2)
{
    __shared__ float red[128];
    int c = blockIdx.x, b = blockIdx.y, d = threadIdx.x;
    float* row = G + ((size_t)b * C + c) * C;
    float nq = fmaxf(sqrtf(norm2[b * C + c]), 1e-12f);
    float nk = fmaxf(sqrtf(norm2[NB * C + b * C + d]), 1e-12f);
    float sv = row[d] / (nq * nk);
    red[d] = sv; __syncthreads();
    for (int off = 64; off > 0; off >>= 1) {
        if (d < off) red[d] = fmaxf(red[d], red[d + off]);
        __syncthreads();
    }
    float mx = red[0]; __syncthreads();
    float e = __expf(sv - mx);
    red[d] = e; __syncthreads();
    for (int off = 64; off > 0; off >>= 1) {
        if (d < off) red[d] += red[d + off];
        __syncthreads();
    }
    row[d] = e / red[0];
}

// ---- K4b: M_b = aw @ A_b (bf16 out) ----
__global__ __launch_bounds__(256) void k_mproj(
    const float* __restrict__ G, const float* __restrict__ aw, u16* __restrict__ M)
{
    __shared__ float As[128 * 16];
    int b = blockIdx.y, d0 = blockIdx.x * 16, tid = threadIdx.x;
    const float* A = G + (size_t)b * C * C;
    #pragma unroll
    for (int i = 0; i < 8; ++i) {
        int idx = tid + 256 * i;
        int cc = idx >> 4, dd = idx & 15;
        As[idx] = A[cc * C + d0 + dd];
    }
    __syncthreads();
    #pragma unroll
    for (int i = 0; i < 8; ++i) {
        int idx = tid + 256 * i;
        int oo = idx >> 4, dd = idx & 15;
        float s = 0.f;
        for (int cc = 0; cc < 128; ++cc)
            s += aw[oo * C + cc] * As[cc * 16 + dd];
        M[((size_t)b * C + oo) * C + d0 + dd] = f2bf(s);
    }
}

// ---- K5: out = M_b @ dwconv3(v_raw) + ab. Depthwise conv fused into staging.
__global__ __launch_bounds__(256) void k_out(
    const u16* __restrict__ M, const float* __restrict__ v,
    const float* __restrict__ vdw, const float* __restrict__ vdb,
    const float* __restrict__ ab, float* __restrict__ out)
{
    __shared__ __align__(16) u16 lds[128 * LSTR];
    const int tid  = threadIdx.x;
    const int lane = tid & 63;
    const int wave = tid >> 6;
    const int m_lo = lane & 15;
    const int quad = lane >> 4;
    const int b   = blockIdx.z;
    const int row = blockIdx.x;          // image row; n0 = row*128
    const int n0  = row * 128;
    const float* Vb = v + (size_t)b * C * HW;

    int rs[3] = { row > 0 ? row - 1 : 0, row, row < 127 ? row + 1 : 127 };
    float rmask[3] = { row > 0 ? 1.f : 0.f, 1.f, row < 127 ? 1.f : 0.f };

    // stage tile: thread handles 8 px x 4 ch, dwconv on the fly
    #pragma unroll
    for (int it = 0; it < 2; ++it) {
        int idx = tid + 256 * it;
        int n8 = idx & 15;               // px group of 8: p0 = n8*8
        int kq = idx >> 4;               // channel quad: ch = kq*4 + j
        int p0 = n8 * 8;
        float lm  = (n8 > 0)  ? 1.f : 0.f;
        float rmx = (n8 < 15) ? 1.f : 0.f;
        int pL = (n8 > 0)  ? p0 - 1 : 0;
        int pR = (n8 < 15) ? p0 + 8 : 127;
        float o[4][8];
        #pragma unroll
        for (int j = 0; j < 4; ++j) {
            int ch = kq * 4 + j;
            const float* pw = vdw + ch * 9;
            float bias = vdb[ch];
            #pragma unroll
            for (int t = 0; t < 8; ++t) o[j][t] = bias;
            const float* plane = Vb + (size_t)ch * HW;
            #pragma unroll
            for (int dy = 0; dy < 3; ++dy) {
                const float* rp = plane + rs[dy] * 128;
                float rm = rmask[dy];
                float win[10];
                f32x4 m0 = *(const f32x4*)(rp + p0);
                f32x4 m1 = *(const f32x4*)(rp + p0 + 4);
                win[0] = rp[pL] * lm * rm;
                win[9] = rp[pR] * rmx * rm;
                #pragma unroll
                for (int q2 = 0; q2 < 4; ++q2) { win[1 + q2] = m0[q2] * rm; win[5 + q2] = m1[q2] * rm; }
                float w0 = pw[dy * 3 + 0], w1 = pw[dy * 3 + 1], w2 = pw[dy * 3 + 2];
                #pragma unroll
                for (int t = 0; t < 8; ++t)
                    o[j][t] += w0 * win[t] + w1 * win[t + 1] + w2 * win[t + 2];
            }
        }
        #pragma unroll
        for (int t = 0; t < 8; ++t) {
            int rw  = p0 + t;
            int n4t = (rw >> 2) & 31;
            int cs  = (kq >> 1) ^ (n4t & 7);
            u32x2 e;
            e.x = (u32)f2bf(o[0][t]) | ((u32)f2bf(o[1][t]) << 16);
            e.y = (u32)f2bf(o[2][t]) | ((u32)f2bf(o[3][t]) << 16);
            *(u32x2*)(lds + rw * LSTR + cs * 8 + (kq & 1) * 4) = e;
        }
    }
    __syncthreads();

    f32x4 acc[2][8];
    mfma_tile(M + (size_t)b * C * C, lds, acc, wave, m_lo, quad);
    __syncthreads();   // staging dead; reuse LDS for fp32 epilogue

    float* ldsf = (float*)lds;
    #pragma unroll
    for (int ph = 0; ph < 2; ++ph) {
        if ((wave >> 1) == ph) {
            #pragma unroll
            for (int mt = 0; mt < 2; ++mt)
                #pragma unroll
                for (int nt = 0; nt < 8; ++nt)
                    #pragma unroll
                    for (int r = 0; r < 4; ++r) {
                        int m = wave * 32 + mt * 16 + quad * 4 + r;
                        int n = nt * 16 + m_lo;
                        ldsf[(m & 63) * FSTR + n] = acc[mt][nt][r] + ab[m];
                    }
        }
        __syncthreads();
        #pragma unroll
        for (int i = 0; i < 8; ++i) {
            int idx = tid + 256 * i;
            int rw = idx >> 5;
            int c4 = idx & 31;
            f32x4 vv = *(const f32x4*)(ldsf + rw * FSTR + c4 * 4);
            *(f32x4*)(out + (size_t)b * C * HW + (size_t)(ph * 64 + rw) * HW + n0 + c4 * 4) = vv;
        }
        __syncthreads();
    }
}

extern "C" void kernel_launch(void* const* d_in, const int* in_sizes, int n_in,
                              void* d_out, int out_size, void* d_ws, size_t ws_size,
                              hipStream_t stream)
{
    float* x         = (float*)d_in[0];   // scribbled: becomes raw v (harness restores)
    const float* qw  = (const float*)d_in[1];
    const float* qbi = (const float*)d_in[2];
    const float* qdw = (const float*)d_in[3];
    const float* qdb = (const float*)d_in[4];
    const float* kw  = (const float*)d_in[5];
    const float* kbi = (const float*)d_in[6];
    const float* kdw = (const float*)d_in[7];
    const float* kdb = (const float*)d_in[8];
    const float* vw  = (const float*)d_in[9];
    const float* vbi = (const float*)d_in[10];
    const float* vdw = (const float*)d_in[11];
    const float* vdb = (const float*)d_in[12];
    const float* aw  = (const float*)d_in[13];
    const float* ab  = (const float*)d_in[14];

    u16* qpl = (u16*)d_out;
    u16* kpl = qpl + (size_t)NB * C * HW;

    float* G     = (float*)d_ws;               // 1 MiB
    float* norm2 = G + (size_t)NB * C * C;     // 16 KiB
    u16*   M     = (u16*)(norm2 + 2 * NB * C); // 0.5 MiB

    hipMemsetAsync(G, 0, (size_t)NB * C * C * sizeof(float), stream);

    k_conv_qkv<<<dim3(HW / 128, 1, NB), 256, 0, stream>>>(x, qw, qbi, kw, kbi, vw, vbi, qpl, kpl);
    k_dw_qk<<<dim3(2 * NB * C), 256, 0, stream>>>(qpl, kpl, qdw, qdb, kdw, kdb, norm2);
    k_gram<<<dim3(16, 2, NB), 256, 0, stream>>>(qpl, kpl, G);
    k_softmax<<<dim3(C, NB), 128, 0, stream>>>(G, norm2);
    k_mproj<<<dim3(8, NB), 256, 0, stream>>>(G, aw, M);
    k_out<<<dim3(HW / 128, 1, NB), 256, 0, stream>>>(M, x, vdw, vdb, ab, (float*)d_out);
}